// Round 11
// baseline (126.056 us; speedup 1.0000x reference)
//
#include <hip/hip_runtime.h>
#include <hip/hip_bf16.h>

typedef __attribute__((ext_vector_type(8))) __bf16 bf16x8;
typedef __attribute__((ext_vector_type(4))) float f32x4;

// 1/sqrt(128) * log2(e): Q pre-scaled so softmax exponents are base-2
#define QSCALE (0.08838834764831845f * 1.4426950408889634f)
// partial slot: 128x128 bf16 O (32768 B) + 128 f32 m + 128 f32 l
#define SLOT_BYTES 33792

static __device__ __forceinline__ int pack2(float a, float b) {
    union { __bf16 h[2]; int u; } x;
    x.h[0] = (__bf16)a; x.h[1] = (__bf16)b;
    return x.u;
}

// online softmax for one 16-row strip, lane owns q-column lo (swapped QK^T).
// defer-max (THR=8): skip O-rescale while per-tile max growth <= 8.
static __device__ __forceinline__ void softmax_strip(f32x4 (&s)[4], float& mr, float& lr,
                                                     f32x4 (&o)[8], int hi) {
    float mloc = s[0][0];
#pragma unroll
    for (int ct = 0; ct < 4; ++ct)
#pragma unroll
        for (int r = 0; r < 4; ++r) mloc = fmaxf(mloc, s[ct][r]);
    mloc = fmaxf(mloc, __shfl_xor(mloc, 16));
    mloc = fmaxf(mloc, __shfl_xor(mloc, 32));

    float alpha = 1.f;
    if (!__all(mloc <= mr + 8.f)) {
        const float mn = fmaxf(mr, mloc);
        alpha = exp2f(mr - mn);
        mr = mn;
        float ao[4];
#pragma unroll
        for (int r = 0; r < 4; ++r) ao[r] = __shfl(alpha, hi * 4 + r);
#pragma unroll
        for (int dt = 0; dt < 8; ++dt)
#pragma unroll
            for (int r = 0; r < 4; ++r) o[dt][r] *= ao[r];
    }
    float rs = 0.f;
#pragma unroll
    for (int ct = 0; ct < 4; ++ct)
#pragma unroll
        for (int r = 0; r < 4; ++r) {
            const float pv = exp2f(s[ct][r] - mr);
            s[ct][r] = pv;
            rs += pv;
        }
    rs += __shfl_xor(rs, 16);
    rs += __shfl_xor(rs, 32);
    lr = lr * alpha + rs;
}

// V staged into LDS in kv-PERMUTED order sigma so that PV A-fragments are
// lane-local (see round 9 derivation).
static __device__ __forceinline__ void store_v_perm(__bf16* V_lds, int row, int u, bf16x8 val) {
    union { bf16x8 v; int2 d[2]; } x; x.v = val;
    const int ua  = 4 * (u >> 2) + 2 * (u & 1);
    const int off = ((u >> 1) & 1) * 8;
    const int sw  = row & 7;
    char* base = (char*)V_lds + row * 128;
    *reinterpret_cast<int2*>(base + ((ua ^ sw) << 4) + off)       = x.d[0];
    *reinterpret_cast<int2*>(base + (((ua + 1) ^ sw) << 4) + off) = x.d[1];
}

// ---------------- Kernel 0: transpose + cast weights (coalesced) ----------
__global__ __launch_bounds__(256) void prep_w(const float* __restrict__ Wq,
                                              const float* __restrict__ Wk,
                                              const float* __restrict__ Wv,
                                              __bf16* __restrict__ Wt) {
    __shared__ float tile[32][33];
    const int bid = blockIdx.x;
    const int p   = bid >> 7;
    const int rem = bid & 127;
    const int kt  = rem >> 2;
    const int ct  = rem & 3;
    const float* W = (p == 0) ? Wq : ((p == 1) ? Wk : Wv);
    const int tr = threadIdx.x >> 5;
    const int tc = threadIdx.x & 31;
#pragma unroll
    for (int pass = 0; pass < 4; ++pass) {
        const int k = kt * 32 + pass * 8 + tr;
        tile[pass * 8 + tr][tc] = W[k * 128 + ct * 32 + tc];
    }
    __syncthreads();
#pragma unroll
    for (int pass = 0; pass < 4; ++pass) {
        const int c = ct * 32 + pass * 8 + tr;
        Wt[p * 131072 + c * 1024 + kt * 32 + tc] = (__bf16)tile[tc][pass * 8 + tr];
    }
}

// ---------------- Kernel 1: fused QKV projection ----------------
// 512 blocks x 512 thr (8 waves). __launch_bounds__(512, 4): 64 KB LDS caps
// occupancy at 2 blocks/CU anyway, so give the allocator the matching
// 128-VGPR budget -- this is what lets st[16] (64 regs) and bp[4][3]
// (48 regs) stay live instead of being rolled into serial chains.
// TWO-PHASE staging (all 16 float4 loads in flight, sched_barrier fence),
// depth-4 circular B prefetch, LDS-routed coalesced epilogue.
__global__ __launch_bounds__(512, 4) void qkv_gemm(const float* __restrict__ x,
                                                   const __bf16* __restrict__ Wt,
                                                   const float* __restrict__ bq,
                                                   const float* __restrict__ bk,
                                                   const float* __restrict__ bv,
                                                   __bf16* __restrict__ qws,
                                                   __bf16* __restrict__ kws,
                                                   __bf16* __restrict__ vT) {
    __shared__ __align__(16) __bf16 xb[32 * 1024];   // 64 KB (reused by epilogue)

    const int tid = threadIdx.x;
    const int w   = tid >> 6;
    const int l   = tid & 63;
    const int lo  = l & 15;
    const int hi  = l >> 4;
    const int r0  = blockIdx.x * 32;

    // ---- phase 1: issue ALL x loads (16 float4 in flight) ----
    float4 st[16];
#pragma unroll
    for (int i = 0; i < 8; ++i) {
        const int ul  = i * 512 + tid;
        const int row = ul >> 7;
        const int u   = ul & 127;
        const float4* src = reinterpret_cast<const float4*>(
            x + (size_t)(r0 + row) * 1024 + u * 8);
        st[2 * i]     = src[0];
        st[2 * i + 1] = src[1];
    }
    __builtin_amdgcn_sched_barrier(0);   // don't sink loads into phase 2
    // ---- phase 2: convert + LDS write ----
#pragma unroll
    for (int i = 0; i < 8; ++i) {
        const int ul  = i * 512 + tid;
        const int row = ul >> 7;
        const int u   = ul & 127;
        const float4 f0 = st[2 * i];
        const float4 f1 = st[2 * i + 1];
        bf16x8 v;
        v[0]=(__bf16)f0.x; v[1]=(__bf16)f0.y; v[2]=(__bf16)f0.z; v[3]=(__bf16)f0.w;
        v[4]=(__bf16)f1.x; v[5]=(__bf16)f1.y; v[6]=(__bf16)f1.z; v[7]=(__bf16)f1.w;
        *reinterpret_cast<bf16x8*>(&xb[row * 1024 + ((u ^ (row & 7)) * 8)]) = v;
    }
    __syncthreads();

    f32x4 acc[2][3];
#pragma unroll
    for (int rt = 0; rt < 2; ++rt)
#pragma unroll
        for (int tt = 0; tt < 3; ++tt) acc[rt][tt] = (f32x4){0.f, 0.f, 0.f, 0.f};

    const int tbase = w * 3;
    const __bf16* wb0 = Wt + ((tbase    ) >> 3) * 131072 + ((tbase    ) & 7) * 16384 + lo * 1024 + hi * 8;
    const __bf16* wb1 = Wt + ((tbase + 1) >> 3) * 131072 + ((tbase + 1) & 7) * 16384 + lo * 1024 + hi * 8;
    const __bf16* wb2 = Wt + ((tbase + 2) >> 3) * 131072 + ((tbase + 2) & 7) * 16384 + lo * 1024 + hi * 8;

    // depth-4 circular prefetch (48 VGPR -- now allocatable)
    bf16x8 bp[4][3];
#pragma unroll
    for (int d = 0; d < 4; ++d) {
        bp[d][0] = *reinterpret_cast<const bf16x8*>(wb0 + d * 32);
        bp[d][1] = *reinterpret_cast<const bf16x8*>(wb1 + d * 32);
        bp[d][2] = *reinterpret_cast<const bf16x8*>(wb2 + d * 32);
    }

#pragma unroll 4
    for (int kc = 0; kc < 32; ++kc) {
        const int slot = kc & 3;
        const int usw = ((kc * 4 + hi) ^ (lo & 7)) * 8;
        bf16x8 a0 = *reinterpret_cast<const bf16x8*>(&xb[lo * 1024 + usw]);
        bf16x8 a1 = *reinterpret_cast<const bf16x8*>(&xb[(16 + lo) * 1024 + usw]);
        acc[0][0] = __builtin_amdgcn_mfma_f32_16x16x32_bf16(a0, bp[slot][0], acc[0][0], 0, 0, 0);
        acc[1][0] = __builtin_amdgcn_mfma_f32_16x16x32_bf16(a1, bp[slot][0], acc[1][0], 0, 0, 0);
        acc[0][1] = __builtin_amdgcn_mfma_f32_16x16x32_bf16(a0, bp[slot][1], acc[0][1], 0, 0, 0);
        acc[1][1] = __builtin_amdgcn_mfma_f32_16x16x32_bf16(a1, bp[slot][1], acc[1][1], 0, 0, 0);
        acc[0][2] = __builtin_amdgcn_mfma_f32_16x16x32_bf16(a0, bp[slot][2], acc[0][2], 0, 0, 0);
        acc[1][2] = __builtin_amdgcn_mfma_f32_16x16x32_bf16(a1, bp[slot][2], acc[1][2], 0, 0, 0);
        if (kc + 4 < 32) {
            bp[slot][0] = *reinterpret_cast<const bf16x8*>(wb0 + (kc + 4) * 32);
            bp[slot][1] = *reinterpret_cast<const bf16x8*>(wb1 + (kc + 4) * 32);
            bp[slot][2] = *reinterpret_cast<const bf16x8*>(wb2 + (kc + 4) * 32);
        }
    }

    // ---- epilogue: acc -> LDS [32][392] (Q|K|V cols 0..383), then coalesced
    __syncthreads();                     // everyone done reading xb
    __bf16* ob = xb;                     // reuse: 32*392*2 = 25 KB
#pragma unroll
    for (int tt = 0; tt < 3; ++tt) {
        const int t    = tbase + tt;
        const int proj = t >> 3;
        const int col  = (t & 7) * 16 + lo;
        const float* bias = (proj == 0) ? bq : ((proj == 1) ? bk : bv);
        const float bb = bias[col];
        const float sc = (proj == 0) ? QSCALE : 1.f;
#pragma unroll
        for (int rt = 0; rt < 2; ++rt) {
#pragma unroll
            for (int r = 0; r < 4; ++r) {
                const int row = rt * 16 + hi * 4 + r;
                ob[row * 392 + t * 16 + lo] = (__bf16)((acc[rt][tt][r] + bb) * sc);
            }
        }
    }
    __syncthreads();

    // Q and K: row-major, 16B chunks (fully coalesced)
    {
        const int row = tid >> 4;        // 0..31
        const int ch  = tid & 15;        // 0..15 -> cols ch*8..+7
        bf16x8 vq = *reinterpret_cast<const bf16x8*>(&ob[row * 392 + ch * 8]);
        bf16x8 vk = *reinterpret_cast<const bf16x8*>(&ob[row * 392 + 128 + ch * 8]);
        *reinterpret_cast<bf16x8*>(&qws[(size_t)(r0 + row) * 128 + ch * 8]) = vq;
        *reinterpret_cast<bf16x8*>(&kws[(size_t)(r0 + row) * 128 + ch * 8]) = vk;
    }
    // V transposed: vT[b][col][s]; thread = (col, 8-row chunk); 4 thr = 64 B
    {
        const int col = tid >> 2;        // 0..127
        const int rc  = tid & 3;         // 0..3
        bf16x8 vv;
#pragma unroll
        for (int j = 0; j < 8; ++j)
            vv[j] = ob[(rc * 8 + j) * 392 + 256 + col];
        const int b_ = r0 >> 12;
        const int s0 = r0 & 4095;
        *reinterpret_cast<bf16x8*>(
            &vT[(size_t)b_ * 524288 + (size_t)col * 4096 + s0 + rc * 8]) = vv;
    }
}

// ---------------- Kernel 2: causal flash attention ----------------
// 8 waves/block, 128 Q rows/block. K[64][128] (XOR-swizzled) + V^T[128][64]
// (kv-PERMUTED + swizzled) in LDS = 32 KB -> 4 blocks/CU. Reg-staged
// prefetch; swapped QK^T in-register softmax (defer-max); PV A-fragments
// built lane-locally via pack2 (no P LDS roundtrip). bf16 partial slots.
__global__ __launch_bounds__(512, 4) void attn(const __bf16* __restrict__ qws,
                                               const __bf16* __restrict__ kws,
                                               const __bf16* __restrict__ vT,
                                               char* __restrict__ part,
                                               float* __restrict__ out,
                                               int NSEG, int SEG, int direct) {
    __shared__ __align__(16) __bf16 K_lds[64 * 128];    // 16 KB
    __shared__ __align__(16) __bf16 V_lds[128 * 64];    // 16 KB (permuted V^T)

    const int tid = threadIdx.x;
    const int w   = tid >> 6;
    const int l   = tid & 63;
    const int lo  = l & 15;
    const int hi  = l >> 4;

    const int sidx = blockIdx.x / NSEG;      // 0..127 strip (128 rows)
    const int seg  = blockIdx.x - sidx * NSEG;
    const int batch = sidx & 3;
    const int mblk  = 31 - (sidx >> 2);      // longest strips first
    const int q0    = mblk * 128;
    const int extent = q0 + 128;

    const int kv_start = seg * SEG;
    if (kv_start >= extent) return;
    const int kv_end = min(kv_start + SEG, extent);
    const int t0 = kv_start >> 6;
    const int t1 = (kv_end + 63) >> 6;

    const int rw = q0 + w * 16;              // wave's first q row

    // staging map: 2 K-units + 2 V-units per thread (full coverage)
    const int tKrow = tid >> 3;              // 0..63
    const int tKu   = (tid & 7) * 2;         // even unit in 0..14
    const int tVrow = tid >> 2;              // 0..127
    const int tVu   = (tid & 3) * 2;         // even unit in 0..6

    const __bf16* kb = kws + (size_t)batch * 524288;
    const __bf16* vb = vT  + (size_t)batch * 524288;

    // Q fragments
    const size_t qoff = (size_t)(batch * 4096 + rw + lo) * 128 + hi * 8;
    bf16x8 qf[4];
#pragma unroll
    for (int dc = 0; dc < 4; ++dc)
        qf[dc] = *reinterpret_cast<const bf16x8*>(qws + qoff + dc * 32);

    // ---- prologue: stage tile t0 ----
    {
        const int kvb = t0 * 64;
        bf16x8 k0 = *reinterpret_cast<const bf16x8*>(kb + (size_t)(kvb + tKrow) * 128 + tKu * 8);
        bf16x8 k1 = *reinterpret_cast<const bf16x8*>(kb + (size_t)(kvb + tKrow) * 128 + tKu * 8 + 8);
        bf16x8 v0 = *reinterpret_cast<const bf16x8*>(vb + (size_t)tVrow * 4096 + kvb + tVu * 8);
        bf16x8 v1 = *reinterpret_cast<const bf16x8*>(vb + (size_t)tVrow * 4096 + kvb + tVu * 8 + 8);
        *reinterpret_cast<bf16x8*>(&K_lds[tKrow * 128 + ((tKu       ^ (tKrow & 7)) * 8)]) = k0;
        *reinterpret_cast<bf16x8*>(&K_lds[tKrow * 128 + (((tKu + 1) ^ (tKrow & 7)) * 8)]) = k1;
        store_v_perm(V_lds, tVrow, tVu,     v0);
        store_v_perm(V_lds, tVrow, tVu + 1, v1);
        __syncthreads();
    }

    f32x4 o[8];
#pragma unroll
    for (int dt = 0; dt < 8; ++dt) o[dt] = (f32x4){0.f, 0.f, 0.f, 0.f};
    float mr = -__builtin_inff();
    float lr = 0.f;

    for (int t = t0; t < t1; ++t) {
        const int kvb = t * 64;
        const bool pfetch = (t + 1 < t1);

        // ---- issue next tile's global loads (fly under compute) ----
        bf16x8 kr0, kr1, vr0, vr1;
        if (pfetch) {
            const int kvn = kvb + 64;
            kr0 = *reinterpret_cast<const bf16x8*>(kb + (size_t)(kvn + tKrow) * 128 + tKu * 8);
            kr1 = *reinterpret_cast<const bf16x8*>(kb + (size_t)(kvn + tKrow) * 128 + tKu * 8 + 8);
            vr0 = *reinterpret_cast<const bf16x8*>(vb + (size_t)tVrow * 4096 + kvn + tVu * 8);
            vr1 = *reinterpret_cast<const bf16x8*>(vb + (size_t)tVrow * 4096 + kvn + tVu * 8 + 8);
        }

        if (kvb <= rw + 15) {
            // ---- S^T = K . Q^T : lane owns q-column lo ----
            f32x4 s[4];
#pragma unroll
            for (int ct = 0; ct < 4; ++ct) s[ct] = (f32x4){0.f, 0.f, 0.f, 0.f};
            const int sw = lo & 7;
            __builtin_amdgcn_s_setprio(1);
#pragma unroll
            for (int ct = 0; ct < 4; ++ct) {
                const int rbase = (ct * 16 + lo) * 128;
#pragma unroll
                for (int dc = 0; dc < 4; ++dc) {
                    bf16x8 kf = *reinterpret_cast<const bf16x8*>(
                        &K_lds[rbase + (((dc * 4 + hi) ^ sw) << 3)]);
                    s[ct] = __builtin_amdgcn_mfma_f32_16x16x32_bf16(kf, qf[dc], s[ct], 0, 0, 0);
                }
            }
            __builtin_amdgcn_s_setprio(0);

            // ---- causal mask (diagonal tile only) ----
            if (kvb + 63 > rw) {
#pragma unroll
                for (int ct = 0; ct < 4; ++ct)
#pragma unroll
                    for (int r = 0; r < 4; ++r)
                        if (kvb + ct * 16 + hi * 4 + r > rw + lo)
                            s[ct][r] = -__builtin_inff();
            }

            // ---- softmax (in-register, defer-max) ----
            softmax_strip(s, mr, lr, o, hi);

            // ---- P -> bf16 A-fragments, lane-local (kv-permuted) ----
            union { int u[4]; bf16x8 v; } pf0, pf1;
            pf0.u[0] = pack2(s[0][0], s[0][1]);
            pf0.u[1] = pack2(s[0][2], s[0][3]);
            pf0.u[2] = pack2(s[1][0], s[1][1]);
            pf0.u[3] = pack2(s[1][2], s[1][3]);
            pf1.u[0] = pack2(s[2][0], s[2][1]);
            pf1.u[1] = pack2(s[2][2], s[2][3]);
            pf1.u[2] = pack2(s[3][0], s[3][1]);
            pf1.u[3] = pack2(s[3][2], s[3][3]);

            // ---- O += P . V (permuted V fragments from LDS) ----
            __builtin_amdgcn_s_setprio(1);
#pragma unroll
            for (int dt = 0; dt < 8; ++dt) {
                const int vbase = (dt * 16 + lo) * 64;
                bf16x8 vf0 = *reinterpret_cast<const bf16x8*>(
                    &V_lds[vbase + ((hi ^ sw) << 3)]);
                o[dt] = __builtin_amdgcn_mfma_f32_16x16x32_bf16(pf0.v, vf0, o[dt], 0, 0, 0);
                bf16x8 vf1 = *reinterpret_cast<const bf16x8*>(
                    &V_lds[vbase + (((4 + hi) ^ sw) << 3)]);
                o[dt] = __builtin_amdgcn_mfma_f32_16x16x32_bf16(pf1.v, vf1, o[dt], 0, 0, 0);
            }
            __builtin_amdgcn_s_setprio(0);
        }

        // ---- commit prefetched tile ----
        if (pfetch) {
            __syncthreads();
            *reinterpret_cast<bf16x8*>(&K_lds[tKrow * 128 + ((tKu       ^ (tKrow & 7)) * 8)]) = kr0;
            *reinterpret_cast<bf16x8*>(&K_lds[tKrow * 128 + (((tKu + 1) ^ (tKrow & 7)) * 8)]) = kr1;
            store_v_perm(V_lds, tVrow, tVu,     vr0);
            store_v_perm(V_lds, tVrow, tVu + 1, vr1);
            __syncthreads();
        }
    }

    // ---- relocate state q-col -> q-row, write ----
    float lro[4], mro[4];
#pragma unroll
    for (int r = 0; r < 4; ++r) {
        lro[r] = __shfl(lr, hi * 4 + r);
        mro[r] = __shfl(mr, hi * 4 + r);
    }

    if (direct) {
#pragma unroll
        for (int dt = 0; dt < 8; ++dt)
#pragma unroll
            for (int r = 0; r < 4; ++r) {
                const size_t row = (size_t)(batch * 4096 + rw + hi * 4 + r);
                out[row * 128 + dt * 16 + lo] = o[dt][r] / lro[r];
            }
    } else {
        char* slot = part + ((size_t)(sidx * NSEG + seg)) * SLOT_BYTES;
        __bf16* so = (__bf16*)slot;
        float*  sf = (float*)(slot + 32768);
        const int rb = w * 16 + hi * 4;      // row-in-block base
#pragma unroll
        for (int dt = 0; dt < 8; ++dt)
#pragma unroll
            for (int r = 0; r < 4; ++r)
                so[(rb + r) * 128 + dt * 16 + lo] = (__bf16)o[dt][r];
        if (lo == 0) {
#pragma unroll
            for (int r = 0; r < 4; ++r) {
                sf[rb + r]       = mro[r];
                sf[128 + rb + r] = lro[r];
            }
        }
    }
}

// ---------------- Kernel 3: combine KV-split partials ----------------
// 1024 blocks x 256 thr: block = (sidx 0..127, 16-row group 0..7).
__global__ __launch_bounds__(256) void combine(const char* __restrict__ part,
                                               float* __restrict__ out,
                                               int NSEG, int SEG) {
    const int sidx = blockIdx.x >> 3;
    const int rg   = blockIdx.x & 7;
    const int batch = sidx & 3;
    const int mblk  = 31 - (sidx >> 2);
    const int extent = mblk * 128 + 128;
    const int nseg  = min(NSEG, (extent + SEG - 1) / SEG);

    const int rl = rg * 16 + (threadIdx.x >> 4);   // 0..127 row within block
    const int c0 = (threadIdx.x & 15) * 8;
    const char* base = part + (size_t)sidx * NSEG * SLOT_BYTES;

    float mj[8];
    float M = -__builtin_inff();
#pragma unroll 8
    for (int j = 0; j < 8; ++j) {
        if (j < nseg) {
            mj[j] = ((const float*)(base + j * SLOT_BYTES + 32768))[rl];
            M = fmaxf(M, mj[j]);
        }
    }
    float wj[8];
    float L = 0.f;
#pragma unroll 8
    for (int j = 0; j < 8; ++j) {
        if (j < nseg) {
            wj[j] = exp2f(mj[j] - M);
            L += ((const float*)(base + j * SLOT_BYTES + 32768))[128 + rl] * wj[j];
        }
    }

    float a[8];
#pragma unroll
    for (int e = 0; e < 8; ++e) a[e] = 0.f;
#pragma unroll 8
    for (int j = 0; j < 8; ++j) {
        if (j < nseg) {
            const bf16x8 ov = *reinterpret_cast<const bf16x8*>(
                base + j * SLOT_BYTES + (size_t)(rl * 128 + c0) * 2);
            const float wgt = wj[j];
#pragma unroll
            for (int e = 0; e < 8; ++e) a[e] += (float)ov[e] * wgt;
        }
    }
    const float inv = 1.f / L;
    float* op = out + ((size_t)(batch * 4096 + mblk * 128 + rl)) * 128 + c0;
    float4* o4 = reinterpret_cast<float4*>(op);
    o4[0] = (float4){a[0]*inv, a[1]*inv, a[2]*inv, a[3]*inv};
    o4[1] = (float4){a[4]*inv, a[5]*inv, a[6]*inv, a[7]*inv};
}

// ---------------- Launch ----------------
extern "C" void kernel_launch(void* const* d_in, const int* in_sizes, int n_in,
                              void* d_out, int out_size, void* d_ws, size_t ws_size,
                              hipStream_t stream) {
    const float* x  = (const float*)d_in[0];
    const float* Wk = (const float*)d_in[1];
    const float* bk = (const float*)d_in[2];
    const float* Wq = (const float*)d_in[3];
    const float* bq = (const float*)d_in[4];
    const float* Wv = (const float*)d_in[5];
    const float* bv = (const float*)d_in[6];
    float* out = (float*)d_out;

    char* ws = (char*)d_ws;
    __bf16* Wt  = (__bf16*)ws;                                // 786432 B
    __bf16* qws = (__bf16*)(ws + 786432);                     // 4 MB
    __bf16* kws = (__bf16*)(ws + 786432 + 4194304);           // 4 MB
    __bf16* vT  = (__bf16*)(ws + 786432 + 2 * 4194304);       // 4 MB
    const size_t base = 786432 + 3 * 4194304;                 // 13369344 B

    // largest KV-split that fits: per NSEG unit = 128 slots * SLOT_BYTES
    const size_t per_seg = 128ull * SLOT_BYTES;
    int NSEG = 1;
    for (int cand = 8; cand >= 2; cand >>= 1) {
        if (base + (size_t)cand * per_seg <= ws_size) { NSEG = cand; break; }
    }
    char* part = ws + base;

    prep_w<<<384, 256, 0, stream>>>(Wq, Wk, Wv, Wt);
    qkv_gemm<<<512, 512, 0, stream>>>(x, Wt, bq, bk, bv, qws, kws, vT);

    if (NSEG >= 2) {
        const int SEG = 4096 / NSEG;
        attn<<<128 * NSEG, 512, 0, stream>>>(qws, kws, vT, part, out, NSEG, SEG, 0);
        combine<<<1024, 256, 0, stream>>>(part, out, NSEG, SEG);
    } else {
        attn<<<128, 512, 0, stream>>>(qws, kws, vT, nullptr, out, 1, 4096, 1);
    }
}

// Round 12
// 100.403 us; speedup vs baseline: 1.2555x; 1.2555x over previous
//
#include <hip/hip_runtime.h>
#include <hip/hip_bf16.h>

typedef __attribute__((ext_vector_type(8))) __bf16 bf16x8;
typedef __attribute__((ext_vector_type(4))) float f32x4;

// 1/sqrt(128) * log2(e): Q pre-scaled so softmax exponents are base-2
#define QSCALE (0.08838834764831845f * 1.4426950408889634f)
// partial slot: 128x128 bf16 O (32768 B) + 128 f32 m + 128 f32 l
#define SLOT_BYTES 33792

static __device__ __forceinline__ int pack2(float a, float b) {
    union { __bf16 h[2]; int u; } x;
    x.h[0] = (__bf16)a; x.h[1] = (__bf16)b;
    return x.u;
}

// online softmax for one 16-row strip, lane owns q-column lo (swapped QK^T).
// defer-max (THR=8): skip O-rescale while per-tile max growth <= 8.
static __device__ __forceinline__ void softmax_strip(f32x4 (&s)[4], float& mr, float& lr,
                                                     f32x4 (&o)[8], int hi) {
    float mloc = s[0][0];
#pragma unroll
    for (int ct = 0; ct < 4; ++ct)
#pragma unroll
        for (int r = 0; r < 4; ++r) mloc = fmaxf(mloc, s[ct][r]);
    mloc = fmaxf(mloc, __shfl_xor(mloc, 16));
    mloc = fmaxf(mloc, __shfl_xor(mloc, 32));

    float alpha = 1.f;
    if (!__all(mloc <= mr + 8.f)) {
        const float mn = fmaxf(mr, mloc);
        alpha = exp2f(mr - mn);
        mr = mn;
        float ao[4];
#pragma unroll
        for (int r = 0; r < 4; ++r) ao[r] = __shfl(alpha, hi * 4 + r);
#pragma unroll
        for (int dt = 0; dt < 8; ++dt)
#pragma unroll
            for (int r = 0; r < 4; ++r) o[dt][r] *= ao[r];
    }
    float rs = 0.f;
#pragma unroll
    for (int ct = 0; ct < 4; ++ct)
#pragma unroll
        for (int r = 0; r < 4; ++r) {
            const float pv = exp2f(s[ct][r] - mr);
            s[ct][r] = pv;
            rs += pv;
        }
    rs += __shfl_xor(rs, 16);
    rs += __shfl_xor(rs, 32);
    lr = lr * alpha + rs;
}

// V staged into LDS in kv-PERMUTED order sigma so that PV A-fragments are
// lane-local (see round 9 derivation).
static __device__ __forceinline__ void store_v_perm(__bf16* V_lds, int row, int u, bf16x8 val) {
    union { bf16x8 v; int2 d[2]; } x; x.v = val;
    const int ua  = 4 * (u >> 2) + 2 * (u & 1);
    const int off = ((u >> 1) & 1) * 8;
    const int sw  = row & 7;
    char* base = (char*)V_lds + row * 128;
    *reinterpret_cast<int2*>(base + ((ua ^ sw) << 4) + off)       = x.d[0];
    *reinterpret_cast<int2*>(base + (((ua + 1) ^ sw) << 4) + off) = x.d[1];
}

// ---------------- Kernel 0: transpose + cast weights (coalesced) ----------
__global__ __launch_bounds__(256) void prep_w(const float* __restrict__ Wq,
                                              const float* __restrict__ Wk,
                                              const float* __restrict__ Wv,
                                              __bf16* __restrict__ Wt) {
    __shared__ float tile[32][33];
    const int bid = blockIdx.x;
    const int p   = bid >> 7;
    const int rem = bid & 127;
    const int kt  = rem >> 2;
    const int ct  = rem & 3;
    const float* W = (p == 0) ? Wq : ((p == 1) ? Wk : Wv);
    const int tr = threadIdx.x >> 5;
    const int tc = threadIdx.x & 31;
#pragma unroll
    for (int pass = 0; pass < 4; ++pass) {
        const int k = kt * 32 + pass * 8 + tr;
        tile[pass * 8 + tr][tc] = W[k * 128 + ct * 32 + tc];
    }
    __syncthreads();
#pragma unroll
    for (int pass = 0; pass < 4; ++pass) {
        const int c = ct * 32 + pass * 8 + tr;
        Wt[p * 131072 + c * 1024 + kt * 32 + tc] = (__bf16)tile[tc][pass * 8 + tr];
    }
}

// ---------------- Kernel 1: fused QKV projection (LDS-staged K-step GEMM) --
// 512 blocks x 512 thr (8 waves). Block = 32 rows x 384 cols; K-loop in 16
// steps of BK=64. Per step: stage B[384][64] bf16 (48 KB) + A[32][64] bf16
// (4 KB) into XOR-swizzled LDS via the attn-proven reg-staging pattern
// (loads issued BEFORE compute, ds_write after barrier -> latency hidden
// under MFMA; 2 blocks/CU overlap each other). Wave (wr,wc): row-tile wr,
// col-tiles wc*6..+5 -> 12 MFMA/step/wave, fragments from LDS only.
__global__ __launch_bounds__(512, 4) void qkv_gemm(const float* __restrict__ x,
                                                   const __bf16* __restrict__ Wt,
                                                   const float* __restrict__ bq,
                                                   const float* __restrict__ bk,
                                                   const float* __restrict__ bv,
                                                   __bf16* __restrict__ qws,
                                                   __bf16* __restrict__ kws,
                                                   __bf16* __restrict__ vT) {
    __shared__ __align__(16) char smem[53248];            // 52 KB
    __bf16* B_lds = (__bf16*)smem;                        // [384][64] swizzled
    __bf16* A_lds = (__bf16*)(smem + 49152);              // [32][64] swizzled

    const int tid = threadIdx.x;
    const int w   = tid >> 6;
    const int l   = tid & 63;
    const int lo  = l & 15;
    const int hi  = l >> 4;
    const int r0  = blockIdx.x * 32;
    const int wr  = w >> 2;          // row-tile 0..1
    const int wc  = w & 3;           // col-group 0..3

    // staging maps (full coverage):
    // B: chunk n = w*6+j (48 x 1KB); lane: c = n*8 + (l>>3), u = l&7
    // A: thread: row = tid>>4 (0..31), q = tid&15 (16B f32 sub-chunk)
    const int arow = tid >> 4, aq = tid & 15;

    bf16x8 bst[6];
    float4 ast;

    auto STAGE_LOAD = [&](int ks) {
#pragma unroll
        for (int j = 0; j < 6; ++j) {
            const int n = w * 6 + j;
            const int c = n * 8 + (l >> 3);
            const int u = l & 7;
            bst[j] = *reinterpret_cast<const bf16x8*>(
                Wt + (size_t)c * 1024 + ks * 64 + u * 8);
        }
        ast = *reinterpret_cast<const float4*>(
            x + (size_t)(r0 + arow) * 1024 + ks * 64 + aq * 4);
    };
    auto STAGE_WRITE = [&]() {
#pragma unroll
        for (int j = 0; j < 6; ++j) {
            const int n = w * 6 + j;
            const int c = n * 8 + (l >> 3);
            const int u = l & 7;
            *reinterpret_cast<bf16x8*>(&B_lds[c * 64 + ((u ^ (c & 7)) << 3)]) = bst[j];
        }
        union { __bf16 h[4]; int2 d; } av;
        av.h[0] = (__bf16)ast.x; av.h[1] = (__bf16)ast.y;
        av.h[2] = (__bf16)ast.z; av.h[3] = (__bf16)ast.w;
        *reinterpret_cast<int2*>((char*)A_lds + arow * 128 +
            (((aq >> 1) ^ (arow & 7)) << 4) + ((aq & 1) << 3)) = av.d;
    };

    f32x4 acc[6];
#pragma unroll
    for (int tt = 0; tt < 6; ++tt) acc[tt] = (f32x4){0.f, 0.f, 0.f, 0.f};

    STAGE_LOAD(0);
    STAGE_WRITE();
    __syncthreads();

    const int lr = wr * 16 + lo;     // A-fragment row
    for (int ks = 0; ks < 16; ++ks) {
        if (ks < 15) STAGE_LOAD(ks + 1);    // loads fly under compute

#pragma unroll
        for (int kc = 0; kc < 2; ++kc) {
            bf16x8 a = *reinterpret_cast<const bf16x8*>(
                &A_lds[lr * 64 + (((kc * 4 + hi) ^ (lr & 7)) << 3)]);
#pragma unroll
            for (int tt = 0; tt < 6; ++tt) {
                const int c = (wc * 6 + tt) * 16 + lo;
                bf16x8 b = *reinterpret_cast<const bf16x8*>(
                    &B_lds[c * 64 + (((kc * 4 + hi) ^ (c & 7)) << 3)]);
                acc[tt] = __builtin_amdgcn_mfma_f32_16x16x32_bf16(a, b, acc[tt], 0, 0, 0);
            }
        }
        __syncthreads();                    // all waves done reading this step
        if (ks < 15) {
            STAGE_WRITE();
            __syncthreads();                // next step's tiles visible
        }
    }

    // ---- epilogue: acc -> LDS [32][392] (Q|K|V cols), then coalesced ----
    __bf16* ob = (__bf16*)smem;             // 25088 B, B/A tiles dead now
#pragma unroll
    for (int tt = 0; tt < 6; ++tt) {
        const int t    = wc * 6 + tt;
        const int proj = t >> 3;
        const int col  = (t & 7) * 16 + lo;
        const float* bias = (proj == 0) ? bq : ((proj == 1) ? bk : bv);
        const float bb = bias[col];
        const float sc = (proj == 0) ? QSCALE : 1.f;
#pragma unroll
        for (int r = 0; r < 4; ++r) {
            const int row = wr * 16 + hi * 4 + r;
            ob[row * 392 + t * 16 + lo] = (__bf16)((acc[tt][r] + bb) * sc);
        }
    }
    __syncthreads();

    // Q and K: row-major, 16B chunks (fully coalesced)
    {
        const int row = tid >> 4;        // 0..31
        const int ch  = tid & 15;        // cols ch*8..+7
        bf16x8 vq = *reinterpret_cast<const bf16x8*>(&ob[row * 392 + ch * 8]);
        bf16x8 vk = *reinterpret_cast<const bf16x8*>(&ob[row * 392 + 128 + ch * 8]);
        *reinterpret_cast<bf16x8*>(&qws[(size_t)(r0 + row) * 128 + ch * 8]) = vq;
        *reinterpret_cast<bf16x8*>(&kws[(size_t)(r0 + row) * 128 + ch * 8]) = vk;
    }
    // V transposed: vT[b][col][s]; thread = (col, 8-row chunk); 4 thr = 64 B
    {
        const int col = tid >> 2;        // 0..127
        const int rc  = tid & 3;         // 0..3
        bf16x8 vv;
#pragma unroll
        for (int j = 0; j < 8; ++j)
            vv[j] = ob[(rc * 8 + j) * 392 + 256 + col];
        const int b_ = r0 >> 12;
        const int s0 = r0 & 4095;
        *reinterpret_cast<bf16x8*>(
            &vT[(size_t)b_ * 524288 + (size_t)col * 4096 + s0 + rc * 8]) = vv;
    }
}

// ---------------- Kernel 2: causal flash attention ----------------
// 8 waves/block, 128 Q rows/block. K[64][128] (XOR-swizzled) + V^T[128][64]
// (kv-PERMUTED + swizzled) in LDS = 32 KB -> 4 blocks/CU. Reg-staged
// prefetch; swapped QK^T in-register softmax (defer-max); PV A-fragments
// built lane-locally via pack2 (no P LDS roundtrip). bf16 partial slots.
__global__ __launch_bounds__(512, 4) void attn(const __bf16* __restrict__ qws,
                                               const __bf16* __restrict__ kws,
                                               const __bf16* __restrict__ vT,
                                               char* __restrict__ part,
                                               float* __restrict__ out,
                                               int NSEG, int SEG, int direct) {
    __shared__ __align__(16) __bf16 K_lds[64 * 128];    // 16 KB
    __shared__ __align__(16) __bf16 V_lds[128 * 64];    // 16 KB (permuted V^T)

    const int tid = threadIdx.x;
    const int w   = tid >> 6;
    const int l   = tid & 63;
    const int lo  = l & 15;
    const int hi  = l >> 4;

    const int sidx = blockIdx.x / NSEG;      // 0..127 strip (128 rows)
    const int seg  = blockIdx.x - sidx * NSEG;
    const int batch = sidx & 3;
    const int mblk  = 31 - (sidx >> 2);      // longest strips first
    const int q0    = mblk * 128;
    const int extent = q0 + 128;

    const int kv_start = seg * SEG;
    if (kv_start >= extent) return;
    const int kv_end = min(kv_start + SEG, extent);
    const int t0 = kv_start >> 6;
    const int t1 = (kv_end + 63) >> 6;

    const int rw = q0 + w * 16;              // wave's first q row

    // staging map: 2 K-units + 2 V-units per thread (full coverage)
    const int tKrow = tid >> 3;              // 0..63
    const int tKu   = (tid & 7) * 2;         // even unit in 0..14
    const int tVrow = tid >> 2;              // 0..127
    const int tVu   = (tid & 3) * 2;         // even unit in 0..6

    const __bf16* kb = kws + (size_t)batch * 524288;
    const __bf16* vb = vT  + (size_t)batch * 524288;

    // Q fragments
    const size_t qoff = (size_t)(batch * 4096 + rw + lo) * 128 + hi * 8;
    bf16x8 qf[4];
#pragma unroll
    for (int dc = 0; dc < 4; ++dc)
        qf[dc] = *reinterpret_cast<const bf16x8*>(qws + qoff + dc * 32);

    // ---- prologue: stage tile t0 ----
    {
        const int kvb = t0 * 64;
        bf16x8 k0 = *reinterpret_cast<const bf16x8*>(kb + (size_t)(kvb + tKrow) * 128 + tKu * 8);
        bf16x8 k1 = *reinterpret_cast<const bf16x8*>(kb + (size_t)(kvb + tKrow) * 128 + tKu * 8 + 8);
        bf16x8 v0 = *reinterpret_cast<const bf16x8*>(vb + (size_t)tVrow * 4096 + kvb + tVu * 8);
        bf16x8 v1 = *reinterpret_cast<const bf16x8*>(vb + (size_t)tVrow * 4096 + kvb + tVu * 8 + 8);
        *reinterpret_cast<bf16x8*>(&K_lds[tKrow * 128 + ((tKu       ^ (tKrow & 7)) * 8)]) = k0;
        *reinterpret_cast<bf16x8*>(&K_lds[tKrow * 128 + (((tKu + 1) ^ (tKrow & 7)) * 8)]) = k1;
        store_v_perm(V_lds, tVrow, tVu,     v0);
        store_v_perm(V_lds, tVrow, tVu + 1, v1);
        __syncthreads();
    }

    f32x4 o[8];
#pragma unroll
    for (int dt = 0; dt < 8; ++dt) o[dt] = (f32x4){0.f, 0.f, 0.f, 0.f};
    float mr = -__builtin_inff();
    float lr = 0.f;

    for (int t = t0; t < t1; ++t) {
        const int kvb = t * 64;
        const bool pfetch = (t + 1 < t1);

        // ---- issue next tile's global loads (fly under compute) ----
        bf16x8 kr0, kr1, vr0, vr1;
        if (pfetch) {
            const int kvn = kvb + 64;
            kr0 = *reinterpret_cast<const bf16x8*>(kb + (size_t)(kvn + tKrow) * 128 + tKu * 8);
            kr1 = *reinterpret_cast<const bf16x8*>(kb + (size_t)(kvn + tKrow) * 128 + tKu * 8 + 8);
            vr0 = *reinterpret_cast<const bf16x8*>(vb + (size_t)tVrow * 4096 + kvn + tVu * 8);
            vr1 = *reinterpret_cast<const bf16x8*>(vb + (size_t)tVrow * 4096 + kvn + tVu * 8 + 8);
        }

        if (kvb <= rw + 15) {
            // ---- S^T = K . Q^T : lane owns q-column lo ----
            f32x4 s[4];
#pragma unroll
            for (int ct = 0; ct < 4; ++ct) s[ct] = (f32x4){0.f, 0.f, 0.f, 0.f};
            const int sw = lo & 7;
            __builtin_amdgcn_s_setprio(1);
#pragma unroll
            for (int ct = 0; ct < 4; ++ct) {
                const int rbase = (ct * 16 + lo) * 128;
#pragma unroll
                for (int dc = 0; dc < 4; ++dc) {
                    bf16x8 kf = *reinterpret_cast<const bf16x8*>(
                        &K_lds[rbase + (((dc * 4 + hi) ^ sw) << 3)]);
                    s[ct] = __builtin_amdgcn_mfma_f32_16x16x32_bf16(kf, qf[dc], s[ct], 0, 0, 0);
                }
            }
            __builtin_amdgcn_s_setprio(0);

            // ---- causal mask (diagonal tile only) ----
            if (kvb + 63 > rw) {
#pragma unroll
                for (int ct = 0; ct < 4; ++ct)
#pragma unroll
                    for (int r = 0; r < 4; ++r)
                        if (kvb + ct * 16 + hi * 4 + r > rw + lo)
                            s[ct][r] = -__builtin_inff();
            }

            // ---- softmax (in-register, defer-max) ----
            softmax_strip(s, mr, lr, o, hi);

            // ---- P -> bf16 A-fragments, lane-local (kv-permuted) ----
            union { int u[4]; bf16x8 v; } pf0, pf1;
            pf0.u[0] = pack2(s[0][0], s[0][1]);
            pf0.u[1] = pack2(s[0][2], s[0][3]);
            pf0.u[2] = pack2(s[1][0], s[1][1]);
            pf0.u[3] = pack2(s[1][2], s[1][3]);
            pf1.u[0] = pack2(s[2][0], s[2][1]);
            pf1.u[1] = pack2(s[2][2], s[2][3]);
            pf1.u[2] = pack2(s[3][0], s[3][1]);
            pf1.u[3] = pack2(s[3][2], s[3][3]);

            // ---- O += P . V (permuted V fragments from LDS) ----
            __builtin_amdgcn_s_setprio(1);
#pragma unroll
            for (int dt = 0; dt < 8; ++dt) {
                const int vbase = (dt * 16 + lo) * 64;
                bf16x8 vf0 = *reinterpret_cast<const bf16x8*>(
                    &V_lds[vbase + ((hi ^ sw) << 3)]);
                o[dt] = __builtin_amdgcn_mfma_f32_16x16x32_bf16(pf0.v, vf0, o[dt], 0, 0, 0);
                bf16x8 vf1 = *reinterpret_cast<const bf16x8*>(
                    &V_lds[vbase + (((4 + hi) ^ sw) << 3)]);
                o[dt] = __builtin_amdgcn_mfma_f32_16x16x32_bf16(pf1.v, vf1, o[dt], 0, 0, 0);
            }
            __builtin_amdgcn_s_setprio(0);
        }

        // ---- commit prefetched tile ----
        if (pfetch) {
            __syncthreads();
            *reinterpret_cast<bf16x8*>(&K_lds[tKrow * 128 + ((tKu       ^ (tKrow & 7)) * 8)]) = kr0;
            *reinterpret_cast<bf16x8*>(&K_lds[tKrow * 128 + (((tKu + 1) ^ (tKrow & 7)) * 8)]) = kr1;
            store_v_perm(V_lds, tVrow, tVu,     vr0);
            store_v_perm(V_lds, tVrow, tVu + 1, vr1);
            __syncthreads();
        }
    }

    // ---- relocate state q-col -> q-row, write ----
    float lro[4], mro[4];
#pragma unroll
    for (int r = 0; r < 4; ++r) {
        lro[r] = __shfl(lr, hi * 4 + r);
        mro[r] = __shfl(mr, hi * 4 + r);
    }

    if (direct) {
#pragma unroll
        for (int dt = 0; dt < 8; ++dt)
#pragma unroll
            for (int r = 0; r < 4; ++r) {
                const size_t row = (size_t)(batch * 4096 + rw + hi * 4 + r);
                out[row * 128 + dt * 16 + lo] = o[dt][r] / lro[r];
            }
    } else {
        char* slot = part + ((size_t)(sidx * NSEG + seg)) * SLOT_BYTES;
        __bf16* so = (__bf16*)slot;
        float*  sf = (float*)(slot + 32768);
        const int rb = w * 16 + hi * 4;      // row-in-block base
#pragma unroll
        for (int dt = 0; dt < 8; ++dt)
#pragma unroll
            for (int r = 0; r < 4; ++r)
                so[(rb + r) * 128 + dt * 16 + lo] = (__bf16)o[dt][r];
        if (lo == 0) {
#pragma unroll
            for (int r = 0; r < 4; ++r) {
                sf[rb + r]       = mro[r];
                sf[128 + rb + r] = lro[r];
            }
        }
    }
}

// ---------------- Kernel 3: combine KV-split partials ----------------
// 1024 blocks x 256 thr: block = (sidx 0..127, 16-row group 0..7).
__global__ __launch_bounds__(256) void combine(const char* __restrict__ part,
                                               float* __restrict__ out,
                                               int NSEG, int SEG) {
    const int sidx = blockIdx.x >> 3;
    const int rg   = blockIdx.x & 7;
    const int batch = sidx & 3;
    const int mblk  = 31 - (sidx >> 2);
    const int extent = mblk * 128 + 128;
    const int nseg  = min(NSEG, (extent + SEG - 1) / SEG);

    const int rl = rg * 16 + (threadIdx.x >> 4);   // 0..127 row within block
    const int c0 = (threadIdx.x & 15) * 8;
    const char* base = part + (size_t)sidx * NSEG * SLOT_BYTES;

    float mj[8];
    float M = -__builtin_inff();
#pragma unroll 8
    for (int j = 0; j < 8; ++j) {
        if (j < nseg) {
            mj[j] = ((const float*)(base + j * SLOT_BYTES + 32768))[rl];
            M = fmaxf(M, mj[j]);
        }
    }
    float wj[8];
    float L = 0.f;
#pragma unroll 8
    for (int j = 0; j < 8; ++j) {
        if (j < nseg) {
            wj[j] = exp2f(mj[j] - M);
            L += ((const float*)(base + j * SLOT_BYTES + 32768))[128 + rl] * wj[j];
        }
    }

    float a[8];
#pragma unroll
    for (int e = 0; e < 8; ++e) a[e] = 0.f;
#pragma unroll 8
    for (int j = 0; j < 8; ++j) {
        if (j < nseg) {
            const bf16x8 ov = *reinterpret_cast<const bf16x8*>(
                base + j * SLOT_BYTES + (size_t)(rl * 128 + c0) * 2);
            const float wgt = wj[j];
#pragma unroll
            for (int e = 0; e < 8; ++e) a[e] += (float)ov[e] * wgt;
        }
    }
    const float inv = 1.f / L;
    float* op = out + ((size_t)(batch * 4096 + mblk * 128 + rl)) * 128 + c0;
    float4* o4 = reinterpret_cast<float4*>(op);
    o4[0] = (float4){a[0]*inv, a[1]*inv, a[2]*inv, a[3]*inv};
    o4[1] = (float4){a[4]*inv, a[5]*inv, a[6]*inv, a[7]*inv};
}

// ---------------- Launch ----------------
extern "C" void kernel_launch(void* const* d_in, const int* in_sizes, int n_in,
                              void* d_out, int out_size, void* d_ws, size_t ws_size,
                              hipStream_t stream) {
    const float* x  = (const float*)d_in[0];
    const float* Wk = (const float*)d_in[1];
    const float* bk = (const float*)d_in[2];
    const float* Wq = (const float*)d_in[3];
    const float* bq = (const float*)d_in[4];
    const float* Wv = (const float*)d_in[5];
    const float* bv = (const float*)d_in[6];
    float* out = (float*)d_out;

    char* ws = (char*)d_ws;
    __bf16* Wt  = (__bf16*)ws;                                // 786432 B
    __bf16* qws = (__bf16*)(ws + 786432);                     // 4 MB
    __bf16* kws = (__bf16*)(ws + 786432 + 4194304);           // 4 MB
    __bf16* vT  = (__bf16*)(ws + 786432 + 2 * 4194304);       // 4 MB
    const size_t base = 786432 + 3 * 4194304;                 // 13369344 B

    // largest KV-split that fits: per NSEG unit = 128 slots * SLOT_BYTES
    const size_t per_seg = 128ull * SLOT_BYTES;
    int NSEG = 1;
    for (int cand = 8; cand >= 2; cand >>= 1) {
        if (base + (size_t)cand * per_seg <= ws_size) { NSEG = cand; break; }
    }
    char* part = ws + base;

    prep_w<<<384, 256, 0, stream>>>(Wq, Wk, Wv, Wt);
    qkv_gemm<<<512, 512, 0, stream>>>(x, Wt, bq, bk, bv, qws, kws, vT);

    if (NSEG >= 2) {
        const int SEG = 4096 / NSEG;
        attn<<<128 * NSEG, 512, 0, stream>>>(qws, kws, vT, part, out, NSEG, SEG, 0);
        combine<<<1024, 256, 0, stream>>>(part, out, NSEG, SEG);
    } else {
        attn<<<128, 512, 0, stream>>>(qws, kws, vT, nullptr, out, 1, 4096, 1);
    }
}

// Round 13
// 100.031 us; speedup vs baseline: 1.2602x; 1.0037x over previous
//
#include <hip/hip_runtime.h>
#include <hip/hip_bf16.h>

typedef __attribute__((ext_vector_type(8))) __bf16 bf16x8;
typedef __attribute__((ext_vector_type(4))) float f32x4;

// 1/sqrt(128) * log2(e): Q pre-scaled so softmax exponents are base-2
#define QSCALE (0.08838834764831845f * 1.4426950408889634f)
// partial slot: 128x128 bf16 O (32768 B) + 128 f32 m + 128 f32 l
#define SLOT_BYTES 33792

static __device__ __forceinline__ int pack2(float a, float b) {
    union { __bf16 h[2]; int u; } x;
    x.h[0] = (__bf16)a; x.h[1] = (__bf16)b;
    return x.u;
}

// online softmax for one 16-row strip, lane owns q-column lo (swapped QK^T).
// defer-max (THR=8): skip O-rescale while per-tile max growth <= 8.
static __device__ __forceinline__ void softmax_strip(f32x4 (&s)[4], float& mr, float& lr,
                                                     f32x4 (&o)[8], int hi) {
    float mloc = s[0][0];
#pragma unroll
    for (int ct = 0; ct < 4; ++ct)
#pragma unroll
        for (int r = 0; r < 4; ++r) mloc = fmaxf(mloc, s[ct][r]);
    mloc = fmaxf(mloc, __shfl_xor(mloc, 16));
    mloc = fmaxf(mloc, __shfl_xor(mloc, 32));

    float alpha = 1.f;
    if (!__all(mloc <= mr + 8.f)) {
        const float mn = fmaxf(mr, mloc);
        alpha = exp2f(mr - mn);
        mr = mn;
        float ao[4];
#pragma unroll
        for (int r = 0; r < 4; ++r) ao[r] = __shfl(alpha, hi * 4 + r);
#pragma unroll
        for (int dt = 0; dt < 8; ++dt)
#pragma unroll
            for (int r = 0; r < 4; ++r) o[dt][r] *= ao[r];
    }
    float rs = 0.f;
#pragma unroll
    for (int ct = 0; ct < 4; ++ct)
#pragma unroll
        for (int r = 0; r < 4; ++r) {
            const float pv = exp2f(s[ct][r] - mr);
            s[ct][r] = pv;
            rs += pv;
        }
    rs += __shfl_xor(rs, 16);
    rs += __shfl_xor(rs, 32);
    lr = lr * alpha + rs;
}

// V staged into LDS in kv-PERMUTED order sigma so that PV A-fragments are
// lane-local (see round 9 derivation).
static __device__ __forceinline__ void store_v_perm(__bf16* V_lds, int row, int u, bf16x8 val) {
    union { bf16x8 v; int2 d[2]; } x; x.v = val;
    const int ua  = 4 * (u >> 2) + 2 * (u & 1);
    const int off = ((u >> 1) & 1) * 8;
    const int sw  = row & 7;
    char* base = (char*)V_lds + row * 128;
    *reinterpret_cast<int2*>(base + ((ua ^ sw) << 4) + off)       = x.d[0];
    *reinterpret_cast<int2*>(base + (((ua + 1) ^ sw) << 4) + off) = x.d[1];
}

// ---------------- Kernel 0: transpose + cast weights (coalesced) ----------
__global__ __launch_bounds__(256) void prep_w(const float* __restrict__ Wq,
                                              const float* __restrict__ Wk,
                                              const float* __restrict__ Wv,
                                              __bf16* __restrict__ Wt) {
    __shared__ float tile[32][33];
    const int bid = blockIdx.x;
    const int p   = bid >> 7;
    const int rem = bid & 127;
    const int kt  = rem >> 2;
    const int ct  = rem & 3;
    const float* W = (p == 0) ? Wq : ((p == 1) ? Wk : Wv);
    const int tr = threadIdx.x >> 5;
    const int tc = threadIdx.x & 31;
#pragma unroll
    for (int pass = 0; pass < 4; ++pass) {
        const int k = kt * 32 + pass * 8 + tr;
        tile[pass * 8 + tr][tc] = W[k * 128 + ct * 32 + tc];
    }
    __syncthreads();
#pragma unroll
    for (int pass = 0; pass < 4; ++pass) {
        const int c = ct * 32 + pass * 8 + tr;
        Wt[p * 131072 + c * 1024 + kt * 32 + tc] = (__bf16)tile[tc][pass * 8 + tr];
    }
}

// ---------------- Kernel 1: fused QKV projection (LDS-staged K-step GEMM) --
// 512 blocks x 512 thr (8 waves). Block = 32 rows x 384 cols; K-loop in 16
// steps of BK=64. Per step: stage B[384][64] bf16 (48 KB) + A[32][64] bf16
// (4 KB) into XOR-swizzled LDS; loads issued BEFORE compute. Wave (wr,wc):
// row-tile wr, col-tiles wc*6..+5 -> 12 MFMA/step/wave, fragments from LDS.
__global__ __launch_bounds__(512, 4) void qkv_gemm(const float* __restrict__ x,
                                                   const __bf16* __restrict__ Wt,
                                                   const float* __restrict__ bq,
                                                   const float* __restrict__ bk,
                                                   const float* __restrict__ bv,
                                                   __bf16* __restrict__ qws,
                                                   __bf16* __restrict__ kws,
                                                   __bf16* __restrict__ vT) {
    __shared__ __align__(16) char smem[53248];            // 52 KB
    __bf16* B_lds = (__bf16*)smem;                        // [384][64] swizzled
    __bf16* A_lds = (__bf16*)(smem + 49152);              // [32][64] swizzled

    const int tid = threadIdx.x;
    const int w   = tid >> 6;
    const int l   = tid & 63;
    const int lo  = l & 15;
    const int hi  = l >> 4;
    const int r0  = blockIdx.x * 32;
    const int wr  = w >> 2;          // row-tile 0..1
    const int wc  = w & 3;           // col-group 0..3

    const int arow = tid >> 4, aq = tid & 15;

    bf16x8 bst[6];
    float4 ast;

    auto STAGE_LOAD = [&](int ks) {
#pragma unroll
        for (int j = 0; j < 6; ++j) {
            const int n = w * 6 + j;
            const int c = n * 8 + (l >> 3);
            const int u = l & 7;
            bst[j] = *reinterpret_cast<const bf16x8*>(
                Wt + (size_t)c * 1024 + ks * 64 + u * 8);
        }
        ast = *reinterpret_cast<const float4*>(
            x + (size_t)(r0 + arow) * 1024 + ks * 64 + aq * 4);
    };
    auto STAGE_WRITE = [&]() {
#pragma unroll
        for (int j = 0; j < 6; ++j) {
            const int n = w * 6 + j;
            const int c = n * 8 + (l >> 3);
            const int u = l & 7;
            *reinterpret_cast<bf16x8*>(&B_lds[c * 64 + ((u ^ (c & 7)) << 3)]) = bst[j];
        }
        union { __bf16 h[4]; int2 d; } av;
        av.h[0] = (__bf16)ast.x; av.h[1] = (__bf16)ast.y;
        av.h[2] = (__bf16)ast.z; av.h[3] = (__bf16)ast.w;
        *reinterpret_cast<int2*>((char*)A_lds + arow * 128 +
            (((aq >> 1) ^ (arow & 7)) << 4) + ((aq & 1) << 3)) = av.d;
    };

    f32x4 acc[6];
#pragma unroll
    for (int tt = 0; tt < 6; ++tt) acc[tt] = (f32x4){0.f, 0.f, 0.f, 0.f};

    STAGE_LOAD(0);
    STAGE_WRITE();
    __syncthreads();

    const int lr = wr * 16 + lo;     // A-fragment row
    for (int ks = 0; ks < 16; ++ks) {
        if (ks < 15) STAGE_LOAD(ks + 1);    // loads fly under compute

#pragma unroll
        for (int kc = 0; kc < 2; ++kc) {
            bf16x8 a = *reinterpret_cast<const bf16x8*>(
                &A_lds[lr * 64 + (((kc * 4 + hi) ^ (lr & 7)) << 3)]);
#pragma unroll
            for (int tt = 0; tt < 6; ++tt) {
                const int c = (wc * 6 + tt) * 16 + lo;
                bf16x8 b = *reinterpret_cast<const bf16x8*>(
                    &B_lds[c * 64 + (((kc * 4 + hi) ^ (c & 7)) << 3)]);
                acc[tt] = __builtin_amdgcn_mfma_f32_16x16x32_bf16(a, b, acc[tt], 0, 0, 0);
            }
        }
        __syncthreads();                    // all waves done reading this step
        if (ks < 15) {
            STAGE_WRITE();
            __syncthreads();                // next step's tiles visible
        }
    }

    // ---- epilogue: acc -> LDS [32][392] (Q|K|V cols), then coalesced ----
    __bf16* ob = (__bf16*)smem;             // 25088 B, B/A tiles dead now
#pragma unroll
    for (int tt = 0; tt < 6; ++tt) {
        const int t    = wc * 6 + tt;
        const int proj = t >> 3;
        const int col  = (t & 7) * 16 + lo;
        const float* bias = (proj == 0) ? bq : ((proj == 1) ? bk : bv);
        const float bb = bias[col];
        const float sc = (proj == 0) ? QSCALE : 1.f;
#pragma unroll
        for (int r = 0; r < 4; ++r) {
            const int row = wr * 16 + hi * 4 + r;
            ob[row * 392 + t * 16 + lo] = (__bf16)((acc[tt][r] + bb) * sc);
        }
    }
    __syncthreads();

    // Q and K: row-major, 16B chunks (fully coalesced)
    {
        const int row = tid >> 4;        // 0..31
        const int ch  = tid & 15;        // cols ch*8..+7
        bf16x8 vq = *reinterpret_cast<const bf16x8*>(&ob[row * 392 + ch * 8]);
        bf16x8 vk = *reinterpret_cast<const bf16x8*>(&ob[row * 392 + 128 + ch * 8]);
        *reinterpret_cast<bf16x8*>(&qws[(size_t)(r0 + row) * 128 + ch * 8]) = vq;
        *reinterpret_cast<bf16x8*>(&kws[(size_t)(r0 + row) * 128 + ch * 8]) = vk;
    }
    // V transposed: vT[b][col][s]; thread = (col, 8-row chunk); 4 thr = 64 B
    {
        const int col = tid >> 2;        // 0..127
        const int rc  = tid & 3;         // 0..3
        bf16x8 vv;
#pragma unroll
        for (int j = 0; j < 8; ++j)
            vv[j] = ob[(rc * 8 + j) * 392 + 256 + col];
        const int b_ = r0 >> 12;
        const int s0 = r0 & 4095;
        *reinterpret_cast<bf16x8*>(
            &vT[(size_t)b_ * 524288 + (size_t)col * 4096 + s0 + rc * 8]) = vv;
    }
}

// ---------------- Kernel 2: causal flash attention (double-buffered) ------
// 8 waves/block, 128 Q rows/block. K[2][64][128] + V^T[2][128][64] LDS
// double-buffer (64 KB): tile t+1's ds_write overlaps tile t's compute,
// ONE barrier per tile (buf^1's readers finished before end-of-(t-1)
// barrier). Swapped QK^T in-register softmax (defer-max); lane-local P
// via kv-permutation; bf16 partial slots.
__global__ __launch_bounds__(512, 4) void attn(const __bf16* __restrict__ qws,
                                               const __bf16* __restrict__ kws,
                                               const __bf16* __restrict__ vT,
                                               char* __restrict__ part,
                                               float* __restrict__ out,
                                               int NSEG, int SEG, int direct) {
    __shared__ __align__(16) __bf16 K_lds[2][64 * 128];    // 32 KB
    __shared__ __align__(16) __bf16 V_lds[2][128 * 64];    // 32 KB (permuted)

    const int tid = threadIdx.x;
    const int w   = tid >> 6;
    const int l   = tid & 63;
    const int lo  = l & 15;
    const int hi  = l >> 4;

    const int sidx = blockIdx.x / NSEG;      // 0..127 strip (128 rows)
    const int seg  = blockIdx.x - sidx * NSEG;
    const int batch = sidx & 3;
    const int mblk  = 31 - (sidx >> 2);      // longest strips first
    const int q0    = mblk * 128;
    const int extent = q0 + 128;

    const int kv_start = seg * SEG;
    if (kv_start >= extent) return;
    const int kv_end = min(kv_start + SEG, extent);
    const int t0 = kv_start >> 6;
    const int t1 = (kv_end + 63) >> 6;

    const int rw = q0 + w * 16;              // wave's first q row

    // staging map: 2 K-units + 2 V-units per thread (full coverage)
    const int tKrow = tid >> 3;              // 0..63
    const int tKu   = (tid & 7) * 2;         // even unit in 0..14
    const int tVrow = tid >> 2;              // 0..127
    const int tVu   = (tid & 3) * 2;         // even unit in 0..6

    const __bf16* kb = kws + (size_t)batch * 524288;
    const __bf16* vb = vT  + (size_t)batch * 524288;

    // Q fragments
    const size_t qoff = (size_t)(batch * 4096 + rw + lo) * 128 + hi * 8;
    bf16x8 qf[4];
#pragma unroll
    for (int dc = 0; dc < 4; ++dc)
        qf[dc] = *reinterpret_cast<const bf16x8*>(qws + qoff + dc * 32);

    // ---- prologue: stage tile t0 into buffer 0 ----
    {
        const int kvb = t0 * 64;
        bf16x8 k0 = *reinterpret_cast<const bf16x8*>(kb + (size_t)(kvb + tKrow) * 128 + tKu * 8);
        bf16x8 k1 = *reinterpret_cast<const bf16x8*>(kb + (size_t)(kvb + tKrow) * 128 + tKu * 8 + 8);
        bf16x8 v0 = *reinterpret_cast<const bf16x8*>(vb + (size_t)tVrow * 4096 + kvb + tVu * 8);
        bf16x8 v1 = *reinterpret_cast<const bf16x8*>(vb + (size_t)tVrow * 4096 + kvb + tVu * 8 + 8);
        *reinterpret_cast<bf16x8*>(&K_lds[0][tKrow * 128 + ((tKu       ^ (tKrow & 7)) * 8)]) = k0;
        *reinterpret_cast<bf16x8*>(&K_lds[0][tKrow * 128 + (((tKu + 1) ^ (tKrow & 7)) * 8)]) = k1;
        store_v_perm(V_lds[0], tVrow, tVu,     v0);
        store_v_perm(V_lds[0], tVrow, tVu + 1, v1);
        __syncthreads();
    }

    f32x4 o[8];
#pragma unroll
    for (int dt = 0; dt < 8; ++dt) o[dt] = (f32x4){0.f, 0.f, 0.f, 0.f};
    float mr = -__builtin_inff();
    float lr = 0.f;

    int cur = 0;
    for (int t = t0; t < t1; ++t) {
        const int kvb = t * 64;
        const bool pfetch = (t + 1 < t1);

        // ---- issue next tile's global loads (fly under compute) ----
        bf16x8 kr0, kr1, vr0, vr1;
        if (pfetch) {
            const int kvn = kvb + 64;
            kr0 = *reinterpret_cast<const bf16x8*>(kb + (size_t)(kvn + tKrow) * 128 + tKu * 8);
            kr1 = *reinterpret_cast<const bf16x8*>(kb + (size_t)(kvn + tKrow) * 128 + tKu * 8 + 8);
            vr0 = *reinterpret_cast<const bf16x8*>(vb + (size_t)tVrow * 4096 + kvn + tVu * 8);
            vr1 = *reinterpret_cast<const bf16x8*>(vb + (size_t)tVrow * 4096 + kvn + tVu * 8 + 8);
        }

        if (kvb <= rw + 15) {
            // ---- S^T = K . Q^T : lane owns q-column lo ----
            f32x4 s[4];
#pragma unroll
            for (int ct = 0; ct < 4; ++ct) s[ct] = (f32x4){0.f, 0.f, 0.f, 0.f};
            const int sw = lo & 7;
            __builtin_amdgcn_s_setprio(1);
#pragma unroll
            for (int ct = 0; ct < 4; ++ct) {
                const int rbase = (ct * 16 + lo) * 128;
#pragma unroll
                for (int dc = 0; dc < 4; ++dc) {
                    bf16x8 kf = *reinterpret_cast<const bf16x8*>(
                        &K_lds[cur][rbase + (((dc * 4 + hi) ^ sw) << 3)]);
                    s[ct] = __builtin_amdgcn_mfma_f32_16x16x32_bf16(kf, qf[dc], s[ct], 0, 0, 0);
                }
            }
            __builtin_amdgcn_s_setprio(0);

            // ---- causal mask (diagonal tile only) ----
            if (kvb + 63 > rw) {
#pragma unroll
                for (int ct = 0; ct < 4; ++ct)
#pragma unroll
                    for (int r = 0; r < 4; ++r)
                        if (kvb + ct * 16 + hi * 4 + r > rw + lo)
                            s[ct][r] = -__builtin_inff();
            }

            // ---- softmax (in-register, defer-max) ----
            softmax_strip(s, mr, lr, o, hi);

            // ---- P -> bf16 A-fragments, lane-local (kv-permuted) ----
            union { int u[4]; bf16x8 v; } pf0, pf1;
            pf0.u[0] = pack2(s[0][0], s[0][1]);
            pf0.u[1] = pack2(s[0][2], s[0][3]);
            pf0.u[2] = pack2(s[1][0], s[1][1]);
            pf0.u[3] = pack2(s[1][2], s[1][3]);
            pf1.u[0] = pack2(s[2][0], s[2][1]);
            pf1.u[1] = pack2(s[2][2], s[2][3]);
            pf1.u[2] = pack2(s[3][0], s[3][1]);
            pf1.u[3] = pack2(s[3][2], s[3][3]);

            // ---- O += P . V (permuted V fragments from LDS) ----
            __builtin_amdgcn_s_setprio(1);
#pragma unroll
            for (int dt = 0; dt < 8; ++dt) {
                const int vbase = (dt * 16 + lo) * 64;
                bf16x8 vf0 = *reinterpret_cast<const bf16x8*>(
                    &V_lds[cur][vbase + ((hi ^ sw) << 3)]);
                o[dt] = __builtin_amdgcn_mfma_f32_16x16x32_bf16(pf0.v, vf0, o[dt], 0, 0, 0);
                bf16x8 vf1 = *reinterpret_cast<const bf16x8*>(
                    &V_lds[cur][vbase + (((4 + hi) ^ sw) << 3)]);
                o[dt] = __builtin_amdgcn_mfma_f32_16x16x32_bf16(pf1.v, vf1, o[dt], 0, 0, 0);
            }
            __builtin_amdgcn_s_setprio(0);
        }

        // ---- commit prefetched tile into the OTHER buffer (no pre-barrier:
        //      its last readers finished before the end-of-previous-tile
        //      barrier), then one barrier to publish ----
        if (pfetch) {
            const int nxt = cur ^ 1;
            *reinterpret_cast<bf16x8*>(&K_lds[nxt][tKrow * 128 + ((tKu       ^ (tKrow & 7)) * 8)]) = kr0;
            *reinterpret_cast<bf16x8*>(&K_lds[nxt][tKrow * 128 + (((tKu + 1) ^ (tKrow & 7)) * 8)]) = kr1;
            store_v_perm(V_lds[nxt], tVrow, tVu,     vr0);
            store_v_perm(V_lds[nxt], tVrow, tVu + 1, vr1);
            __syncthreads();
            cur = nxt;
        }
    }

    // ---- relocate state q-col -> q-row, write ----
    float lro[4], mro[4];
#pragma unroll
    for (int r = 0; r < 4; ++r) {
        lro[r] = __shfl(lr, hi * 4 + r);
        mro[r] = __shfl(mr, hi * 4 + r);
    }

    if (direct) {
#pragma unroll
        for (int dt = 0; dt < 8; ++dt)
#pragma unroll
            for (int r = 0; r < 4; ++r) {
                const size_t row = (size_t)(batch * 4096 + rw + hi * 4 + r);
                out[row * 128 + dt * 16 + lo] = o[dt][r] / lro[r];
            }
    } else {
        char* slot = part + ((size_t)(sidx * NSEG + seg)) * SLOT_BYTES;
        __bf16* so = (__bf16*)slot;
        float*  sf = (float*)(slot + 32768);
        const int rb = w * 16 + hi * 4;      // row-in-block base
#pragma unroll
        for (int dt = 0; dt < 8; ++dt)
#pragma unroll
            for (int r = 0; r < 4; ++r)
                so[(rb + r) * 128 + dt * 16 + lo] = (__bf16)o[dt][r];
        if (lo == 0) {
#pragma unroll
            for (int r = 0; r < 4; ++r) {
                sf[rb + r]       = mro[r];
                sf[128 + rb + r] = lro[r];
            }
        }
    }
}

// ---------------- Kernel 3: combine KV-split partials ----------------
// 1024 blocks x 256 thr: block = (sidx 0..127, 16-row group 0..7).
__global__ __launch_bounds__(256) void combine(const char* __restrict__ part,
                                               float* __restrict__ out,
                                               int NSEG, int SEG) {
    const int sidx = blockIdx.x >> 3;
    const int rg   = blockIdx.x & 7;
    const int batch = sidx & 3;
    const int mblk  = 31 - (sidx >> 2);
    const int extent = mblk * 128 + 128;
    const int nseg  = min(NSEG, (extent + SEG - 1) / SEG);

    const int rl = rg * 16 + (threadIdx.x >> 4);   // 0..127 row within block
    const int c0 = (threadIdx.x & 15) * 8;
    const char* base = part + (size_t)sidx * NSEG * SLOT_BYTES;

    float mj[8];
    float M = -__builtin_inff();
#pragma unroll 8
    for (int j = 0; j < 8; ++j) {
        if (j < nseg) {
            mj[j] = ((const float*)(base + j * SLOT_BYTES + 32768))[rl];
            M = fmaxf(M, mj[j]);
        }
    }
    float wj[8];
    float L = 0.f;
#pragma unroll 8
    for (int j = 0; j < 8; ++j) {
        if (j < nseg) {
            wj[j] = exp2f(mj[j] - M);
            L += ((const float*)(base + j * SLOT_BYTES + 32768))[128 + rl] * wj[j];
        }
    }

    float a[8];
#pragma unroll
    for (int e = 0; e < 8; ++e) a[e] = 0.f;
#pragma unroll 8
    for (int j = 0; j < 8; ++j) {
        if (j < nseg) {
            const bf16x8 ov = *reinterpret_cast<const bf16x8*>(
                base + j * SLOT_BYTES + (size_t)(rl * 128 + c0) * 2);
            const float wgt = wj[j];
#pragma unroll
            for (int e = 0; e < 8; ++e) a[e] += (float)ov[e] * wgt;
        }
    }
    const float inv = 1.f / L;
    float* op = out + ((size_t)(batch * 4096 + mblk * 128 + rl)) * 128 + c0;
    float4* o4 = reinterpret_cast<float4*>(op);
    o4[0] = (float4){a[0]*inv, a[1]*inv, a[2]*inv, a[3]*inv};
    o4[1] = (float4){a[4]*inv, a[5]*inv, a[6]*inv, a[7]*inv};
}

// ---------------- Launch ----------------
extern "C" void kernel_launch(void* const* d_in, const int* in_sizes, int n_in,
                              void* d_out, int out_size, void* d_ws, size_t ws_size,
                              hipStream_t stream) {
    const float* x  = (const float*)d_in[0];
    const float* Wk = (const float*)d_in[1];
    const float* bk = (const float*)d_in[2];
    const float* Wq = (const float*)d_in[3];
    const float* bq = (const float*)d_in[4];
    const float* Wv = (const float*)d_in[5];
    const float* bv = (const float*)d_in[6];
    float* out = (float*)d_out;

    char* ws = (char*)d_ws;
    __bf16* Wt  = (__bf16*)ws;                                // 786432 B
    __bf16* qws = (__bf16*)(ws + 786432);                     // 4 MB
    __bf16* kws = (__bf16*)(ws + 786432 + 4194304);           // 4 MB
    __bf16* vT  = (__bf16*)(ws + 786432 + 2 * 4194304);       // 4 MB
    const size_t base = 786432 + 3 * 4194304;                 // 13369344 B

    // largest KV-split that fits: per NSEG unit = 128 slots * SLOT_BYTES
    const size_t per_seg = 128ull * SLOT_BYTES;
    int NSEG = 1;
    for (int cand = 8; cand >= 2; cand >>= 1) {
        if (base + (size_t)cand * per_seg <= ws_size) { NSEG = cand; break; }
    }
    char* part = ws + base;

    prep_w<<<384, 256, 0, stream>>>(Wq, Wk, Wv, Wt);
    qkv_gemm<<<512, 512, 0, stream>>>(x, Wt, bq, bk, bv, qws, kws, vT);

    if (NSEG >= 2) {
        const int SEG = 4096 / NSEG;
        attn<<<128 * NSEG, 512, 0, stream>>>(qws, kws, vT, part, out, NSEG, SEG, 0);
        combine<<<1024, 256, 0, stream>>>(part, out, NSEG, SEG);
    } else {
        attn<<<128, 512, 0, stream>>>(qws, kws, vT, nullptr, out, 1, 4096, 1);
    }
}